// Round 7
// baseline (315.095 us; speedup 1.0000x reference)
//
#include <hip/hip_runtime.h>
#include <hip/hip_bf16.h>

typedef short short8 __attribute__((ext_vector_type(8)));
typedef short short4v __attribute__((ext_vector_type(4)));
typedef unsigned int uint4v __attribute__((ext_vector_type(4)));
typedef float f32x4 __attribute__((ext_vector_type(4)));

typedef const __attribute__((address_space(1))) unsigned int* gas_ptr;
typedef __attribute__((address_space(3))) unsigned int* las_ptr;
// async global->LDS, 16B/lane; LDS dest = wave-uniform base + lane*16 (m97/m104)
#define ASYNC16(g, l) __builtin_amdgcn_global_load_lds((gas_ptr)(g), (las_ptr)(l), 16, 0, 0)

__device__ __forceinline__ unsigned short f2bf(float f) {
    unsigned int u = __builtin_bit_cast(unsigned int, f);
    u += 0x7fff + ((u >> 16) & 1);   // RNE
    return (unsigned short)(u >> 16);
}
__device__ __forceinline__ float bf2f(unsigned short s) {
    unsigned int u = (unsigned int)s << 16;
    return __builtin_bit_cast(float, u);
}
__device__ __forceinline__ unsigned int pkbf_trunc(float lo, float hi) {
    return __builtin_amdgcn_perm(__builtin_bit_cast(unsigned int, hi),
                                 __builtin_bit_cast(unsigned int, lo), 0x07060302u);
}

// ---------------------------------------------------------------- fused prep:
// blocks [0,4096): cast x->bf16 ; [4096,4864): transpose w_qkv ; [4864,5120): transpose w_out
__device__ __forceinline__ void transpose_tile(
    const float* __restrict__ w, unsigned short* __restrict__ wt,
    int K, int N, int k0, int n0, unsigned short* tile)
{
    for (int i = threadIdx.x; i < 64 * 64; i += 256) {
        int r = i >> 6, c = i & 63;
        tile[r * 65 + c] = f2bf(w[(size_t)(k0 + r) * N + n0 + c]);
    }
    __syncthreads();
    for (int i = threadIdx.x; i < 64 * 64; i += 256) {
        int r = i >> 6, c = i & 63;
        wt[(size_t)(n0 + r) * K + k0 + c] = tile[c * 65 + r];
    }
}

__global__ __launch_bounds__(256) void prep(
    const float* __restrict__ x, const float* __restrict__ w_qkv,
    const float* __restrict__ w_out,
    unsigned short* __restrict__ x_b, unsigned short* __restrict__ wqkv_t,
    unsigned short* __restrict__ wout_t)
{
    __shared__ unsigned short tile[64 * 65];
    int bid = blockIdx.x;
    if (bid < 4096) {
        int i = (bid * 256 + threadIdx.x) * 4;
        float4 v = *(const float4*)(x + i);
        ushort4 o;
        o.x = f2bf(v.x); o.y = f2bf(v.y); o.z = f2bf(v.z); o.w = f2bf(v.w);
        *(ushort4*)(x_b + i) = o;
    } else if (bid < 4096 + 768) {
        int t = bid - 4096;
        transpose_tile(w_qkv, wqkv_t, 1024, 3072, (t / 48) * 64, (t % 48) * 64, tile);
    } else {
        int t = bid - 4864;
        transpose_tile(w_out, wout_t, 1024, 1024, (t >> 4) * 64, (t & 15) * 64, tile);
    }
}

// ---------------------------------------------------------------- GEMM: C = A * Bt^T + bias
// m97 structure. QKV mode: cols [0,2048) -> qkv (stride 2048); cols [2048,3072) -> vT

template<bool OUT_BF16, bool QKV>
__global__ __launch_bounds__(256, 3) void gemm_bt(
    const unsigned short* __restrict__ A,
    const unsigned short* __restrict__ Bt,
    const float* __restrict__ bias,
    void* __restrict__ C,
    unsigned short* __restrict__ vTp,
    int M, int N, int K)
{
    __shared__ __align__(16) unsigned short As[128 * 32];
    __shared__ __align__(16) unsigned short Bs[128 * 32];
    const int tid = threadIdx.x;
    const int lane = tid & 63;
    const int wave = tid >> 6;
    const int wr = wave >> 1, wc = wave & 1;
    const int m0 = blockIdx.x * 128, n0 = blockIdx.y * 128;
    const int fr = lane & 15, fq = lane >> 4;

    f32x4 acc[4][4] = {};

    const int grow = lane >> 2;
    const int gcol = (lane & 3) * 8;
    const unsigned short* Ag = A  + (size_t)(m0 + wave * 32 + grow) * K + gcol;
    const unsigned short* Bg = Bt + (size_t)(n0 + wave * 32 + grow) * K + gcol;
    unsigned short* AsW0 = As + (wave * 32) * 32;
    unsigned short* AsW1 = As + (wave * 32 + 16) * 32;
    unsigned short* BsW0 = Bs + (wave * 32) * 32;
    unsigned short* BsW1 = Bs + (wave * 32 + 16) * 32;

    for (int k0 = 0; k0 < K; k0 += 32) {
        __syncthreads();
        ASYNC16(Ag + k0,          AsW0);
        ASYNC16(Ag + 16 * K + k0, AsW1);
        ASYNC16(Bg + k0,          BsW0);
        ASYNC16(Bg + 16 * K + k0, BsW1);
        __syncthreads();

        short8 af[4], bfr[4];
#pragma unroll
        for (int i = 0; i < 4; i++)
            af[i] = *(const short8*)(As + (wr * 64 + i * 16 + fr) * 32 + fq * 8);
#pragma unroll
        for (int j = 0; j < 4; j++)
            bfr[j] = *(const short8*)(Bs + (wc * 64 + j * 16 + fr) * 32 + fq * 8);
#pragma unroll
        for (int i = 0; i < 4; i++)
#pragma unroll
            for (int j = 0; j < 4; j++)
                acc[i][j] = __builtin_amdgcn_mfma_f32_16x16x32_bf16(af[i], bfr[j], acc[i][j], 0, 0, 0);
    }

#pragma unroll
    for (int i = 0; i < 4; i++)
#pragma unroll
        for (int j = 0; j < 4; j++) {
            int col = n0 + wc * 64 + j * 16 + fr;
            float bv = bias[col];
            if (QKV && col >= 2048) {
                int hh = (col - 2048) >> 6, d = col & 63;
#pragma unroll
                for (int r = 0; r < 4; r++) {
                    int row = m0 + wr * 64 + i * 16 + fq * 4 + r;
                    int bb = row >> 11, s = row & 2047;
                    vTp[((size_t)(bb * 16 + hh) * 64 + d) * 2048 + s] = f2bf(acc[i][j][r] + bv);
                }
            } else {
                const int cstride = QKV ? 2048 : N;
#pragma unroll
                for (int r = 0; r < 4; r++) {
                    int row = m0 + wr * 64 + i * 16 + fq * 4 + r;
                    float v = acc[i][j][r] + bv;
                    if (OUT_BF16)
                        ((unsigned short*)C)[(size_t)row * cstride + col] = f2bf(v);
                    else
                        ((float*)C)[(size_t)row * cstride + col] = v;
                }
            }
        }
}

// ---------------------------------------------------------------- flash attention (causal, 3-way key-split)
// TRANSPOSED-SCORE scheme: S^T = mfma(kf, qf) puts scores at [key=fq*4+r][q=fr].
// With PV key-order sigma(ks, fq*8+j) = (2ks+(j>>2))*16 + fq*4 + (j&3), the exp'd
// packed pairs ARE the PV B-fragment (P) in registers -> NO P LDS round-trip.
// V A-fragments read in the same sigma order (two ds_read_b64 per tile).
// O accumulates transposed: D[d=fq*4+r][q=fr]. l via mfma(ones, pf).
// Fixed-shift softmax p=exp(s/8-8) => key-split partials exactly additive.

template<int RG0>   // 0: all 4 rg active; 2: only rg2,3 (jt > p)
__device__ __forceinline__ void attn_step(
    const unsigned short* __restrict__ Ks0, const unsigned short* __restrict__ Ks1,
    const unsigned short* __restrict__ Vs0, const unsigned short* __restrict__ Vs1,
    const short8 (&qf)[4][2], const short8 ones,
    f32x4 (&o_acc)[4][4], f32x4 (&l_acc)[4],
    int j0, int fr, int fq,
    const int (&qrow0)[4], bool diagA, bool diagB)
{
    short8 kf[4][2];
#pragma unroll
    for (int t = 0; t < 4; t++) {
        kf[t][0] = *(const short8*)(Ks0 + (t * 16 + fr) * 32 + fq * 8);
        kf[t][1] = *(const short8*)(Ks1 + (t * 16 + fr) * 32 + fq * 8);
    }

    short8 pf[4][2];   // per-rg PV B-fragments, assembled in registers
#pragma unroll
    for (int rg = RG0; rg < 4; rg++) {
        f32x4 s[4];
#pragma unroll
        for (int t = 0; t < 4; t++) {
            s[t] = (f32x4){0.f, 0.f, 0.f, 0.f};
            // SWAPPED operands: D = S^T tile, [key=fq*4+r][q=fr]
            s[t] = __builtin_amdgcn_mfma_f32_16x16x32_bf16(kf[t][0], qf[rg][0], s[t], 0, 0, 0);
            s[t] = __builtin_amdgcn_mfma_f32_16x16x32_bf16(kf[t][1], qf[rg][1], s[t], 0, 0, 0);
        }
        const bool diag = (rg < 2) ? diagA : diagB;
        unsigned int pk[4][2];
        if (diag) {   // wave-uniform branch: mask cost only on diagonal tiles
            const int qq = qrow0[rg] + fr;
#pragma unroll
            for (int t = 0; t < 4; t++) {
                const int keyb = j0 + t * 16 + fq * 4;
                float p[4];
#pragma unroll
                for (int r = 0; r < 4; r++) {
                    float v = __expf(s[t][r] * 0.125f - 8.0f);
                    if (keyb + r > qq) v = 0.f;
                    p[r] = v;
                }
                pk[t][0] = pkbf_trunc(p[0], p[1]);
                pk[t][1] = pkbf_trunc(p[2], p[3]);
            }
        } else {
#pragma unroll
            for (int t = 0; t < 4; t++) {
                float p[4];
#pragma unroll
                for (int r = 0; r < 4; r++)
                    p[r] = __expf(s[t][r] * 0.125f - 8.0f);
                pk[t][0] = pkbf_trunc(p[0], p[1]);
                pk[t][1] = pkbf_trunc(p[2], p[3]);
            }
        }
        pf[rg][0] = __builtin_bit_cast(short8, (uint4v){pk[0][0], pk[0][1], pk[1][0], pk[1][1]});
        pf[rg][1] = __builtin_bit_cast(short8, (uint4v){pk[2][0], pk[2][1], pk[3][0], pk[3][1]});
    }

    // O^T += V^T P ; l += 1 P    (A = V fragment in sigma key-order, B = pf)
#pragma unroll
    for (int ks = 0; ks < 2; ks++) {
        const unsigned short* Vsb = ks ? Vs1 : Vs0;
#pragma unroll
        for (int t = 0; t < 4; t++) {
            short4v vlo = *(const short4v*)(Vsb + (t * 16 + fr) * 32 + fq * 4);
            short4v vhi = *(const short4v*)(Vsb + (t * 16 + fr) * 32 + 16 + fq * 4);
            short8 vf = (short8){vlo[0], vlo[1], vlo[2], vlo[3], vhi[0], vhi[1], vhi[2], vhi[3]};
#pragma unroll
            for (int rg = RG0; rg < 4; rg++)
                o_acc[rg][t] = __builtin_amdgcn_mfma_f32_16x16x32_bf16(vf, pf[rg][ks], o_acc[rg][t], 0, 0, 0);
        }
#pragma unroll
        for (int rg = RG0; rg < 4; rg++)
            l_acc[rg] = __builtin_amdgcn_mfma_f32_16x16x32_bf16(ones, pf[rg][ks], l_acc[rg], 0, 0, 0);
    }
}

__global__ __launch_bounds__(128, 3) void flash_attn(
    const unsigned short* __restrict__ qkv,   // (B*S, 2048): Q | K
    const unsigned short* __restrict__ vT,    // (B*16 heads, 64 dims, 2048 keys)
    unsigned short* __restrict__ Opart,       // [3][B*S][1024] bf16 partial O
    float* __restrict__ lpart)                // [3][B*S][16] f32 partial l
{
    const int gid = blockIdx.x;               // 1536
    const int bh = gid & 31;                  // fastest -> same-bh blocks on same XCD
    const int sl = gid >> 5;                  // 0..47
    const int p  = sl & 15;                   // q-tile pair {p, 31-p}
    const int g  = sl >> 4;                   // key third 0..2
    const int h = bh & 15, b = bh >> 4;
    const int tid = threadIdx.x, wave = tid >> 6, lane = tid & 63;
    const int fr = lane & 15, fq = lane >> 4;
    const size_t RS = 2048;

    const unsigned short* Qb = qkv + (size_t)b * 2048 * RS + h * 64;
    const unsigned short* Kb = Qb + 1024;
    const unsigned short* Vt = vT + (size_t)(b * 16 + h) * 64 * 2048;

    __shared__ __align__(16) unsigned short Ks[2][64 * 32];   // [dim-half][key][32 dims]
    __shared__ __align__(16) unsigned short Vs[2][64 * 32];   // [key-half][dim][32 keys]

    short8 qf[4][2];
    int qrow0[4];
#pragma unroll
    for (int rg = 0; rg < 4; rg++) {
        int qt = (rg < 2) ? p : (31 - p);
        qrow0[rg] = qt * 64 + wave * 32 + (rg & 1) * 16;
        const unsigned short* qrow = Qb + (size_t)(qrow0[rg] + fr) * RS;
        qf[rg][0] = *(const short8*)(qrow + fq * 8);
        qf[rg][1] = *(const short8*)(qrow + 32 + fq * 8);
    }
    short8 ones;
#pragma unroll
    for (int e = 0; e < 8; e++) ones[e] = (short)0x3F80;

    f32x4 o_acc[4][4] = {};
    f32x4 l_acc[4] = {};

    const int grow = lane >> 2;
    const int gcol = (lane & 3) * 8;
    const unsigned short* Kg = Kb + (size_t)(wave * 32 + grow) * RS + gcol;
    const unsigned short* Vg = Vt + (size_t)(wave * 32 + grow) * 2048 + gcol;
    unsigned short* KsW00 = Ks[0] + (wave * 32) * 32;
    unsigned short* KsW01 = Ks[0] + (wave * 32 + 16) * 32;
    unsigned short* KsW10 = Ks[1] + (wave * 32) * 32;
    unsigned short* KsW11 = Ks[1] + (wave * 32 + 16) * 32;
    unsigned short* VsW00 = Vs[0] + (wave * 32) * 32;
    unsigned short* VsW01 = Vs[0] + (wave * 32 + 16) * 32;
    unsigned short* VsW10 = Vs[1] + (wave * 32) * 32;
    unsigned short* VsW11 = Vs[1] + (wave * 32 + 16) * 32;

    // balanced 3-way split over weighted units (4 while jt<=p, else 2; total 66)
    const int njt = 32 - p;
    int lo = (g == 0) ? 0 : njt;
    int hi = njt;
    {
        int cum = 0;
        bool flo = (g == 0), fhi = false;
        for (int j = 0; j < njt; j++) {
            if (!flo && cum >= 44 * g)        { lo = j; flo = true; }
            if (!fhi && cum >= 44 * (g + 1))  { hi = j; fhi = true; }
            cum += (j <= p) ? 8 : 4;
        }
    }

    for (int jt = lo; jt < hi; jt++) {
        const int j0 = jt * 64;
        __syncthreads();
        ASYNC16(Kg + (size_t)j0 * RS,               KsW00);
        ASYNC16(Kg + (size_t)(j0 + 16) * RS,        KsW01);
        ASYNC16(Kg + (size_t)j0 * RS + 32,          KsW10);
        ASYNC16(Kg + (size_t)(j0 + 16) * RS + 32,   KsW11);
        ASYNC16(Vg + j0,               VsW00);
        ASYNC16(Vg + 16 * 2048 + j0,   VsW01);
        ASYNC16(Vg + j0 + 32,          VsW10);
        ASYNC16(Vg + 16 * 2048 + j0 + 32, VsW11);
        __syncthreads();

        bool diagA = (jt == p), diagB = (jt == 31 - p);
        if (jt <= p)
            attn_step<0>(Ks[0], Ks[1], Vs[0], Vs[1], qf, ones,
                         o_acc, l_acc, j0, fr, fq, qrow0, diagA, diagB);
        else
            attn_step<2>(Ks[0], Ks[1], Vs[0], Vs[1], qf, ones,
                         o_acc, l_acc, j0, fr, fq, qrow0, diagA, diagB);
    }

    // write partials: O^T layout -> lane (fr,fq) holds O[q=qrow0+fr][d=t*16+fq*4+r]
    unsigned short* Og = Opart + (size_t)g * 4096 * 1024;
    float* lg = lpart + (size_t)g * 4096 * 16;
#pragma unroll
    for (int rg = 0; rg < 4; rg++) {
        const size_t rowbase = (size_t)(b * 2048 + qrow0[rg] + fr) * 1024 + h * 64;
#pragma unroll
        for (int t = 0; t < 4; t++) {
            ushort4 o;
            o.x = f2bf(o_acc[rg][t][0]); o.y = f2bf(o_acc[rg][t][1]);
            o.z = f2bf(o_acc[rg][t][2]); o.w = f2bf(o_acc[rg][t][3]);
            *(ushort4*)(Og + rowbase + t * 16 + fq * 4) = o;
        }
        if (fq == 0)
            lg[(size_t)(b * 2048 + qrow0[rg] + fr) * 16 + h] = l_acc[rg][0];
    }
}

// ---------------------------------------------------------------- combine key-split partials (3-way)
__global__ __launch_bounds__(256) void reduce_attn(
    const unsigned short* __restrict__ Opart, const float* __restrict__ lpart,
    unsigned short* __restrict__ out)
{
    const size_t OP = (size_t)4096 * 1024, LP = (size_t)4096 * 16;
    int i = (blockIdx.x * 256 + threadIdx.x) * 8;     // over 4096*1024
    int row = i >> 10, h = (i & 1023) >> 6;
    float lsum = lpart[row * 16 + h] + lpart[LP + row * 16 + h] + lpart[2 * LP + row * 16 + h];
    float inv = 1.0f / lsum;
    float acc[8];
#pragma unroll
    for (int e = 0; e < 8; e++) acc[e] = 0.f;
#pragma unroll
    for (int gpart = 0; gpart < 3; gpart++) {
        ushort4 a0 = *(const ushort4*)(Opart + gpart * OP + i);
        ushort4 a1 = *(const ushort4*)(Opart + gpart * OP + i + 4);
        acc[0] += bf2f(a0.x); acc[1] += bf2f(a0.y); acc[2] += bf2f(a0.z); acc[3] += bf2f(a0.w);
        acc[4] += bf2f(a1.x); acc[5] += bf2f(a1.y); acc[6] += bf2f(a1.z); acc[7] += bf2f(a1.w);
    }
    ushort4 o0, o1;
    o0.x = f2bf(acc[0] * inv); o0.y = f2bf(acc[1] * inv);
    o0.z = f2bf(acc[2] * inv); o0.w = f2bf(acc[3] * inv);
    o1.x = f2bf(acc[4] * inv); o1.y = f2bf(acc[5] * inv);
    o1.z = f2bf(acc[6] * inv); o1.w = f2bf(acc[7] * inv);
    *(ushort4*)(out + i) = o0;
    *(ushort4*)(out + i + 4) = o1;
}

// ----------------------------------------------------------------
extern "C" void kernel_launch(void* const* d_in, const int* in_sizes, int n_in,
                              void* d_out, int out_size, void* d_ws, size_t ws_size,
                              hipStream_t stream) {
    const float* x      = (const float*)d_in[0];
    const float* w_qkv  = (const float*)d_in[1];
    const float* b_qkv  = (const float*)d_in[2];
    const float* w_out  = (const float*)d_in[3];
    const float* b_out  = (const float*)d_in[4];
    float* out = (float*)d_out;

    // Workspace layout (60 MB, dead-region reuse: Opart overlays x_b+wqkv_t which
    // die after the QKV GEMM):
    char* ws = (char*)d_ws;
    const size_t MB = 1024 * 1024;
    unsigned short* qkv    = (unsigned short*)(ws);              //  0..16  (gemm1 -> flash)
    unsigned short* vT     = (unsigned short*)(ws + 16 * MB);    // 16..24  (gemm1 -> flash)
    unsigned short* wout_t = (unsigned short*)(ws + 24 * MB);    // 24..26  (prep -> gemm2)
    unsigned short* attn   = (unsigned short*)(ws + 26 * MB);    // 26..34  (reduce -> gemm2)
    float*          lpart  = (float*)         (ws + 34 * MB);    // 34..35  (flash -> reduce)
    unsigned short* x_b    = (unsigned short*)(ws + 36 * MB);    // 36..44  (prep -> gemm1, dead after)
    unsigned short* wqkv_t = (unsigned short*)(ws + 44 * MB);    // 44..50  (prep -> gemm1, dead after)
    unsigned short* Opart  = (unsigned short*)(ws + 36 * MB);    // 36..60  (flash -> reduce; reuses dead region)

    prep<<<5120, 256, 0, stream>>>(x, w_qkv, w_out, x_b, wqkv_t, wout_t);
    gemm_bt<true, true ><<<dim3(32, 24), 256, 0, stream>>>(x_b,  wqkv_t, b_qkv, qkv, vT, 4096, 3072, 1024);
    flash_attn<<<1536, 128, 0, stream>>>(qkv, vT, Opart, lpart);
    reduce_attn<<<2048, 256, 0, stream>>>(Opart, lpart, attn);
    gemm_bt<false, false><<<dim3(32, 8),  256, 0, stream>>>(attn, wout_t, b_out, out, nullptr, 4096, 1024, 1024);
}

// Round 8
// 212.029 us; speedup vs baseline: 1.4861x; 1.4861x over previous
//
#include <hip/hip_runtime.h>
#include <hip/hip_bf16.h>

typedef short short8 __attribute__((ext_vector_type(8)));
typedef short short4v __attribute__((ext_vector_type(4)));
typedef unsigned int uint4v __attribute__((ext_vector_type(4)));
typedef float f32x4 __attribute__((ext_vector_type(4)));

typedef const __attribute__((address_space(1))) unsigned int* gas_ptr;
typedef __attribute__((address_space(3))) unsigned int* las_ptr;
// async global->LDS, 16B/lane; LDS dest = wave-uniform base + lane*16 (m97/m104)
#define ASYNC16(g, l) __builtin_amdgcn_global_load_lds((gas_ptr)(g), (las_ptr)(l), 16, 0, 0)

__device__ __forceinline__ unsigned short f2bf(float f) {
    unsigned int u = __builtin_bit_cast(unsigned int, f);
    u += 0x7fff + ((u >> 16) & 1);   // RNE
    return (unsigned short)(u >> 16);
}
__device__ __forceinline__ float bf2f(unsigned short s) {
    unsigned int u = (unsigned int)s << 16;
    return __builtin_bit_cast(float, u);
}
__device__ __forceinline__ unsigned int pkbf_trunc(float lo, float hi) {
    return __builtin_amdgcn_perm(__builtin_bit_cast(unsigned int, hi),
                                 __builtin_bit_cast(unsigned int, lo), 0x07060302u);
}

// ---------------------------------------------------------------- fused prep:
// blocks [0,4096): cast x->bf16 ; [4096,4864): transpose w_qkv ; [4864,5120): transpose w_out
__device__ __forceinline__ void transpose_tile(
    const float* __restrict__ w, unsigned short* __restrict__ wt,
    int K, int N, int k0, int n0, unsigned short* tile)
{
    for (int i = threadIdx.x; i < 64 * 64; i += 256) {
        int r = i >> 6, c = i & 63;
        tile[r * 65 + c] = f2bf(w[(size_t)(k0 + r) * N + n0 + c]);
    }
    __syncthreads();
    for (int i = threadIdx.x; i < 64 * 64; i += 256) {
        int r = i >> 6, c = i & 63;
        wt[(size_t)(n0 + r) * K + k0 + c] = tile[c * 65 + r];
    }
}

__global__ __launch_bounds__(256) void prep(
    const float* __restrict__ x, const float* __restrict__ w_qkv,
    const float* __restrict__ w_out,
    unsigned short* __restrict__ x_b, unsigned short* __restrict__ wqkv_t,
    unsigned short* __restrict__ wout_t)
{
    __shared__ unsigned short tile[64 * 65];
    int bid = blockIdx.x;
    if (bid < 4096) {
        int i = (bid * 256 + threadIdx.x) * 4;
        float4 v = *(const float4*)(x + i);
        ushort4 o;
        o.x = f2bf(v.x); o.y = f2bf(v.y); o.z = f2bf(v.z); o.w = f2bf(v.w);
        *(ushort4*)(x_b + i) = o;
    } else if (bid < 4096 + 768) {
        int t = bid - 4096;
        transpose_tile(w_qkv, wqkv_t, 1024, 3072, (t / 48) * 64, (t % 48) * 64, tile);
    } else {
        int t = bid - 4864;
        transpose_tile(w_out, wout_t, 1024, 1024, (t >> 4) * 64, (t & 15) * 64, tile);
    }
}

// ---------------------------------------------------------------- GEMM: C = A * Bt^T + bias
// m97 structure. QKV mode: cols [0,2048) -> qkv (stride 2048); cols [2048,3072) -> vT

template<bool OUT_BF16, bool QKV>
__global__ __launch_bounds__(256, 3) void gemm_bt(
    const unsigned short* __restrict__ A,
    const unsigned short* __restrict__ Bt,
    const float* __restrict__ bias,
    void* __restrict__ C,
    unsigned short* __restrict__ vTp,
    int M, int N, int K)
{
    __shared__ __align__(16) unsigned short As[128 * 32];
    __shared__ __align__(16) unsigned short Bs[128 * 32];
    const int tid = threadIdx.x;
    const int lane = tid & 63;
    const int wave = tid >> 6;
    const int wr = wave >> 1, wc = wave & 1;
    const int m0 = blockIdx.x * 128, n0 = blockIdx.y * 128;
    const int fr = lane & 15, fq = lane >> 4;

    f32x4 acc[4][4] = {};

    const int grow = lane >> 2;
    const int gcol = (lane & 3) * 8;
    const unsigned short* Ag = A  + (size_t)(m0 + wave * 32 + grow) * K + gcol;
    const unsigned short* Bg = Bt + (size_t)(n0 + wave * 32 + grow) * K + gcol;
    unsigned short* AsW0 = As + (wave * 32) * 32;
    unsigned short* AsW1 = As + (wave * 32 + 16) * 32;
    unsigned short* BsW0 = Bs + (wave * 32) * 32;
    unsigned short* BsW1 = Bs + (wave * 32 + 16) * 32;

    for (int k0 = 0; k0 < K; k0 += 32) {
        __syncthreads();
        ASYNC16(Ag + k0,          AsW0);
        ASYNC16(Ag + 16 * K + k0, AsW1);
        ASYNC16(Bg + k0,          BsW0);
        ASYNC16(Bg + 16 * K + k0, BsW1);
        __syncthreads();

        short8 af[4], bfr[4];
#pragma unroll
        for (int i = 0; i < 4; i++)
            af[i] = *(const short8*)(As + (wr * 64 + i * 16 + fr) * 32 + fq * 8);
#pragma unroll
        for (int j = 0; j < 4; j++)
            bfr[j] = *(const short8*)(Bs + (wc * 64 + j * 16 + fr) * 32 + fq * 8);
#pragma unroll
        for (int i = 0; i < 4; i++)
#pragma unroll
            for (int j = 0; j < 4; j++)
                acc[i][j] = __builtin_amdgcn_mfma_f32_16x16x32_bf16(af[i], bfr[j], acc[i][j], 0, 0, 0);
    }

#pragma unroll
    for (int i = 0; i < 4; i++)
#pragma unroll
        for (int j = 0; j < 4; j++) {
            int col = n0 + wc * 64 + j * 16 + fr;
            float bv = bias[col];
            if (QKV && col >= 2048) {
                int hh = (col - 2048) >> 6, d = col & 63;
#pragma unroll
                for (int r = 0; r < 4; r++) {
                    int row = m0 + wr * 64 + i * 16 + fq * 4 + r;
                    int bb = row >> 11, s = row & 2047;
                    vTp[((size_t)(bb * 16 + hh) * 64 + d) * 2048 + s] = f2bf(acc[i][j][r] + bv);
                }
            } else {
                const int cstride = QKV ? 2048 : N;
#pragma unroll
                for (int r = 0; r < 4; r++) {
                    int row = m0 + wr * 64 + i * 16 + fq * 4 + r;
                    float v = acc[i][j][r] + bv;
                    if (OUT_BF16)
                        ((unsigned short*)C)[(size_t)row * cstride + col] = f2bf(v);
                    else
                        ((float*)C)[(size_t)row * cstride + col] = v;
                }
            }
        }
}

// ---------------------------------------------------------------- flash attention (causal, 3-way key-split)
// TRANSPOSED-SCORE scheme: S^T = mfma(kf, qf) puts scores at [key=fq*4+r][q=fr].
// With PV key-order sigma(ks, fq*8+j) = (2ks+(j>>2))*16 + fq*4 + (j&3), the exp'd
// packed pairs ARE the PV B-fragment (P) in registers -> NO P LDS round-trip.
// V A-fragments read in the same sigma order (two ds_read_b64 per tile).
// O accumulates transposed: D[d=fq*4+r][q=fr]. l via mfma(ones, pf).
// Fixed-shift softmax p=exp(s/8-8) => key-split partials exactly additive.
// NOTE: ~210 VGPRs live (o_acc 64 + qf/kf/pf 96 + l/addr) -> launch_bounds(128,2).
// (128,3) capped the allocator at 170 and spilled o_acc to scratch: 700 MB HBM
// traffic, 170 us (R7). Do not tighten without shrinking live state first.

template<int RG0>   // 0: all 4 rg active; 2: only rg2,3 (jt > p)
__device__ __forceinline__ void attn_step(
    const unsigned short* __restrict__ Ks0, const unsigned short* __restrict__ Ks1,
    const unsigned short* __restrict__ Vs0, const unsigned short* __restrict__ Vs1,
    const short8 (&qf)[4][2], const short8 ones,
    f32x4 (&o_acc)[4][4], f32x4 (&l_acc)[4],
    int j0, int fr, int fq,
    const int (&qrow0)[4], bool diagA, bool diagB)
{
    short8 kf[4][2];
#pragma unroll
    for (int t = 0; t < 4; t++) {
        kf[t][0] = *(const short8*)(Ks0 + (t * 16 + fr) * 32 + fq * 8);
        kf[t][1] = *(const short8*)(Ks1 + (t * 16 + fr) * 32 + fq * 8);
    }

    short8 pf[4][2];   // per-rg PV B-fragments, assembled in registers
#pragma unroll
    for (int rg = RG0; rg < 4; rg++) {
        f32x4 s[4];
#pragma unroll
        for (int t = 0; t < 4; t++) {
            s[t] = (f32x4){0.f, 0.f, 0.f, 0.f};
            // SWAPPED operands: D = S^T tile, [key=fq*4+r][q=fr]
            s[t] = __builtin_amdgcn_mfma_f32_16x16x32_bf16(kf[t][0], qf[rg][0], s[t], 0, 0, 0);
            s[t] = __builtin_amdgcn_mfma_f32_16x16x32_bf16(kf[t][1], qf[rg][1], s[t], 0, 0, 0);
        }
        const bool diag = (rg < 2) ? diagA : diagB;
        unsigned int pk[4][2];
        if (diag) {   // wave-uniform branch: mask cost only on diagonal tiles
            const int qq = qrow0[rg] + fr;
#pragma unroll
            for (int t = 0; t < 4; t++) {
                const int keyb = j0 + t * 16 + fq * 4;
                float p[4];
#pragma unroll
                for (int r = 0; r < 4; r++) {
                    float v = __expf(s[t][r] * 0.125f - 8.0f);
                    if (keyb + r > qq) v = 0.f;
                    p[r] = v;
                }
                pk[t][0] = pkbf_trunc(p[0], p[1]);
                pk[t][1] = pkbf_trunc(p[2], p[3]);
            }
        } else {
#pragma unroll
            for (int t = 0; t < 4; t++) {
                float p[4];
#pragma unroll
                for (int r = 0; r < 4; r++)
                    p[r] = __expf(s[t][r] * 0.125f - 8.0f);
                pk[t][0] = pkbf_trunc(p[0], p[1]);
                pk[t][1] = pkbf_trunc(p[2], p[3]);
            }
        }
        pf[rg][0] = __builtin_bit_cast(short8, (uint4v){pk[0][0], pk[0][1], pk[1][0], pk[1][1]});
        pf[rg][1] = __builtin_bit_cast(short8, (uint4v){pk[2][0], pk[2][1], pk[3][0], pk[3][1]});
    }

    // O^T += V^T P ; l += 1 P    (A = V fragment in sigma key-order, B = pf)
#pragma unroll
    for (int ks = 0; ks < 2; ks++) {
        const unsigned short* Vsb = ks ? Vs1 : Vs0;
#pragma unroll
        for (int t = 0; t < 4; t++) {
            short4v vlo = *(const short4v*)(Vsb + (t * 16 + fr) * 32 + fq * 4);
            short4v vhi = *(const short4v*)(Vsb + (t * 16 + fr) * 32 + 16 + fq * 4);
            short8 vf = (short8){vlo[0], vlo[1], vlo[2], vlo[3], vhi[0], vhi[1], vhi[2], vhi[3]};
#pragma unroll
            for (int rg = RG0; rg < 4; rg++)
                o_acc[rg][t] = __builtin_amdgcn_mfma_f32_16x16x32_bf16(vf, pf[rg][ks], o_acc[rg][t], 0, 0, 0);
        }
#pragma unroll
        for (int rg = RG0; rg < 4; rg++)
            l_acc[rg] = __builtin_amdgcn_mfma_f32_16x16x32_bf16(ones, pf[rg][ks], l_acc[rg], 0, 0, 0);
    }
}

__global__ __launch_bounds__(128, 2) void flash_attn(
    const unsigned short* __restrict__ qkv,   // (B*S, 2048): Q | K
    const unsigned short* __restrict__ vT,    // (B*16 heads, 64 dims, 2048 keys)
    unsigned short* __restrict__ Opart,       // [3][B*S][1024] bf16 partial O
    float* __restrict__ lpart)                // [3][B*S][16] f32 partial l
{
    const int gid = blockIdx.x;               // 1536
    const int bh = gid & 31;                  // fastest -> same-bh blocks on same XCD
    const int sl = gid >> 5;                  // 0..47
    const int p  = sl & 15;                   // q-tile pair {p, 31-p}
    const int g  = sl >> 4;                   // key third 0..2
    const int h = bh & 15, b = bh >> 4;
    const int tid = threadIdx.x, wave = tid >> 6, lane = tid & 63;
    const int fr = lane & 15, fq = lane >> 4;
    const size_t RS = 2048;

    const unsigned short* Qb = qkv + (size_t)b * 2048 * RS + h * 64;
    const unsigned short* Kb = Qb + 1024;
    const unsigned short* Vt = vT + (size_t)(b * 16 + h) * 64 * 2048;

    __shared__ __align__(16) unsigned short Ks[2][64 * 32];   // [dim-half][key][32 dims]
    __shared__ __align__(16) unsigned short Vs[2][64 * 32];   // [key-half][dim][32 keys]

    short8 qf[4][2];
    int qrow0[4];
#pragma unroll
    for (int rg = 0; rg < 4; rg++) {
        int qt = (rg < 2) ? p : (31 - p);
        qrow0[rg] = qt * 64 + wave * 32 + (rg & 1) * 16;
        const unsigned short* qrow = Qb + (size_t)(qrow0[rg] + fr) * RS;
        qf[rg][0] = *(const short8*)(qrow + fq * 8);
        qf[rg][1] = *(const short8*)(qrow + 32 + fq * 8);
    }
    short8 ones;
#pragma unroll
    for (int e = 0; e < 8; e++) ones[e] = (short)0x3F80;

    f32x4 o_acc[4][4] = {};
    f32x4 l_acc[4] = {};

    const int grow = lane >> 2;
    const int gcol = (lane & 3) * 8;
    const unsigned short* Kg = Kb + (size_t)(wave * 32 + grow) * RS + gcol;
    const unsigned short* Vg = Vt + (size_t)(wave * 32 + grow) * 2048 + gcol;
    unsigned short* KsW00 = Ks[0] + (wave * 32) * 32;
    unsigned short* KsW01 = Ks[0] + (wave * 32 + 16) * 32;
    unsigned short* KsW10 = Ks[1] + (wave * 32) * 32;
    unsigned short* KsW11 = Ks[1] + (wave * 32 + 16) * 32;
    unsigned short* VsW00 = Vs[0] + (wave * 32) * 32;
    unsigned short* VsW01 = Vs[0] + (wave * 32 + 16) * 32;
    unsigned short* VsW10 = Vs[1] + (wave * 32) * 32;
    unsigned short* VsW11 = Vs[1] + (wave * 32 + 16) * 32;

    // balanced 3-way split over weighted units (4 while jt<=p, else 2; total 66)
    const int njt = 32 - p;
    int lo = (g == 0) ? 0 : njt;
    int hi = njt;
    {
        int cum = 0;
        bool flo = (g == 0), fhi = false;
        for (int j = 0; j < njt; j++) {
            if (!flo && cum >= 44 * g)        { lo = j; flo = true; }
            if (!fhi && cum >= 44 * (g + 1))  { hi = j; fhi = true; }
            cum += (j <= p) ? 8 : 4;
        }
    }

    for (int jt = lo; jt < hi; jt++) {
        const int j0 = jt * 64;
        __syncthreads();
        ASYNC16(Kg + (size_t)j0 * RS,               KsW00);
        ASYNC16(Kg + (size_t)(j0 + 16) * RS,        KsW01);
        ASYNC16(Kg + (size_t)j0 * RS + 32,          KsW10);
        ASYNC16(Kg + (size_t)(j0 + 16) * RS + 32,   KsW11);
        ASYNC16(Vg + j0,               VsW00);
        ASYNC16(Vg + 16 * 2048 + j0,   VsW01);
        ASYNC16(Vg + j0 + 32,          VsW10);
        ASYNC16(Vg + 16 * 2048 + j0 + 32, VsW11);
        __syncthreads();

        bool diagA = (jt == p), diagB = (jt == 31 - p);
        if (jt <= p)
            attn_step<0>(Ks[0], Ks[1], Vs[0], Vs[1], qf, ones,
                         o_acc, l_acc, j0, fr, fq, qrow0, diagA, diagB);
        else
            attn_step<2>(Ks[0], Ks[1], Vs[0], Vs[1], qf, ones,
                         o_acc, l_acc, j0, fr, fq, qrow0, diagA, diagB);
    }

    // write partials: O^T layout -> lane (fr,fq) holds O[q=qrow0+fr][d=t*16+fq*4+r]
    unsigned short* Og = Opart + (size_t)g * 4096 * 1024;
    float* lg = lpart + (size_t)g * 4096 * 16;
#pragma unroll
    for (int rg = 0; rg < 4; rg++) {
        const size_t rowbase = (size_t)(b * 2048 + qrow0[rg] + fr) * 1024 + h * 64;
#pragma unroll
        for (int t = 0; t < 4; t++) {
            ushort4 o;
            o.x = f2bf(o_acc[rg][t][0]); o.y = f2bf(o_acc[rg][t][1]);
            o.z = f2bf(o_acc[rg][t][2]); o.w = f2bf(o_acc[rg][t][3]);
            *(ushort4*)(Og + rowbase + t * 16 + fq * 4) = o;
        }
        if (fq == 0)
            lg[(size_t)(b * 2048 + qrow0[rg] + fr) * 16 + h] = l_acc[rg][0];
    }
}

// ---------------------------------------------------------------- combine key-split partials (3-way)
__global__ __launch_bounds__(256) void reduce_attn(
    const unsigned short* __restrict__ Opart, const float* __restrict__ lpart,
    unsigned short* __restrict__ out)
{
    const size_t OP = (size_t)4096 * 1024, LP = (size_t)4096 * 16;
    int i = (blockIdx.x * 256 + threadIdx.x) * 8;     // over 4096*1024
    int row = i >> 10, h = (i & 1023) >> 6;
    float lsum = lpart[row * 16 + h] + lpart[LP + row * 16 + h] + lpart[2 * LP + row * 16 + h];
    float inv = 1.0f / lsum;
    float acc[8];
#pragma unroll
    for (int e = 0; e < 8; e++) acc[e] = 0.f;
#pragma unroll
    for (int gpart = 0; gpart < 3; gpart++) {
        ushort4 a0 = *(const ushort4*)(Opart + gpart * OP + i);
        ushort4 a1 = *(const ushort4*)(Opart + gpart * OP + i + 4);
        acc[0] += bf2f(a0.x); acc[1] += bf2f(a0.y); acc[2] += bf2f(a0.z); acc[3] += bf2f(a0.w);
        acc[4] += bf2f(a1.x); acc[5] += bf2f(a1.y); acc[6] += bf2f(a1.z); acc[7] += bf2f(a1.w);
    }
    ushort4 o0, o1;
    o0.x = f2bf(acc[0] * inv); o0.y = f2bf(acc[1] * inv);
    o0.z = f2bf(acc[2] * inv); o0.w = f2bf(acc[3] * inv);
    o1.x = f2bf(acc[4] * inv); o1.y = f2bf(acc[5] * inv);
    o1.z = f2bf(acc[6] * inv); o1.w = f2bf(acc[7] * inv);
    *(ushort4*)(out + i) = o0;
    *(ushort4*)(out + i + 4) = o1;
}

// ----------------------------------------------------------------
extern "C" void kernel_launch(void* const* d_in, const int* in_sizes, int n_in,
                              void* d_out, int out_size, void* d_ws, size_t ws_size,
                              hipStream_t stream) {
    const float* x      = (const float*)d_in[0];
    const float* w_qkv  = (const float*)d_in[1];
    const float* b_qkv  = (const float*)d_in[2];
    const float* w_out  = (const float*)d_in[3];
    const float* b_out  = (const float*)d_in[4];
    float* out = (float*)d_out;

    // Workspace layout (60 MB, dead-region reuse: Opart overlays x_b+wqkv_t which
    // die after the QKV GEMM):
    char* ws = (char*)d_ws;
    const size_t MB = 1024 * 1024;
    unsigned short* qkv    = (unsigned short*)(ws);              //  0..16  (gemm1 -> flash)
    unsigned short* vT     = (unsigned short*)(ws + 16 * MB);    // 16..24  (gemm1 -> flash)
    unsigned short* wout_t = (unsigned short*)(ws + 24 * MB);    // 24..26  (prep -> gemm2)
    unsigned short* attn   = (unsigned short*)(ws + 26 * MB);    // 26..34  (reduce -> gemm2)
    float*          lpart  = (float*)         (ws + 34 * MB);    // 34..35  (flash -> reduce)
    unsigned short* x_b    = (unsigned short*)(ws + 36 * MB);    // 36..44  (prep -> gemm1, dead after)
    unsigned short* wqkv_t = (unsigned short*)(ws + 44 * MB);    // 44..50  (prep -> gemm1, dead after)
    unsigned short* Opart  = (unsigned short*)(ws + 36 * MB);    // 36..60  (flash -> reduce; reuses dead region)

    prep<<<5120, 256, 0, stream>>>(x, w_qkv, w_out, x_b, wqkv_t, wout_t);
    gemm_bt<true, true ><<<dim3(32, 24), 256, 0, stream>>>(x_b,  wqkv_t, b_qkv, qkv, vT, 4096, 3072, 1024);
    flash_attn<<<1536, 128, 0, stream>>>(qkv, vT, Opart, lpart);
    reduce_attn<<<2048, 256, 0, stream>>>(Opart, lpart, attn);
    gemm_bt<false, false><<<dim3(32, 8),  256, 0, stream>>>(attn, wout_t, b_out, out, nullptr, 4096, 1024, 1024);
}

// Round 9
// 194.223 us; speedup vs baseline: 1.6223x; 1.0917x over previous
//
#include <hip/hip_runtime.h>
#include <hip/hip_bf16.h>

typedef short short8 __attribute__((ext_vector_type(8)));
typedef short short4v __attribute__((ext_vector_type(4)));
typedef unsigned int uint4v __attribute__((ext_vector_type(4)));
typedef float f32x4 __attribute__((ext_vector_type(4)));

typedef const __attribute__((address_space(1))) unsigned int* gas_ptr;
typedef __attribute__((address_space(3))) unsigned int* las_ptr;
// async global->LDS, 16B/lane; LDS dest = wave-uniform base + lane*16 (m97/m104)
#define ASYNC16(g, l) __builtin_amdgcn_global_load_lds((gas_ptr)(g), (las_ptr)(l), 16, 0, 0)

__device__ __forceinline__ unsigned short f2bf(float f) {
    unsigned int u = __builtin_bit_cast(unsigned int, f);
    u += 0x7fff + ((u >> 16) & 1);   // RNE
    return (unsigned short)(u >> 16);
}
__device__ __forceinline__ float bf2f(unsigned short s) {
    unsigned int u = (unsigned int)s << 16;
    return __builtin_bit_cast(float, u);
}
__device__ __forceinline__ unsigned int pkbf_trunc(float lo, float hi) {
    return __builtin_amdgcn_perm(__builtin_bit_cast(unsigned int, hi),
                                 __builtin_bit_cast(unsigned int, lo), 0x07060302u);
}

// ---------------------------------------------------------------- fused prep:
// blocks [0,4096): cast x->bf16 ; [4096,4864): transpose w_qkv ; [4864,5120): transpose w_out
__device__ __forceinline__ void transpose_tile(
    const float* __restrict__ w, unsigned short* __restrict__ wt,
    int K, int N, int k0, int n0, unsigned short* tile)
{
    for (int i = threadIdx.x; i < 64 * 64; i += 256) {
        int r = i >> 6, c = i & 63;
        tile[r * 65 + c] = f2bf(w[(size_t)(k0 + r) * N + n0 + c]);
    }
    __syncthreads();
    for (int i = threadIdx.x; i < 64 * 64; i += 256) {
        int r = i >> 6, c = i & 63;
        wt[(size_t)(n0 + r) * K + k0 + c] = tile[c * 65 + r];
    }
}

__global__ __launch_bounds__(256) void prep(
    const float* __restrict__ x, const float* __restrict__ w_qkv,
    const float* __restrict__ w_out,
    unsigned short* __restrict__ x_b, unsigned short* __restrict__ wqkv_t,
    unsigned short* __restrict__ wout_t)
{
    __shared__ unsigned short tile[64 * 65];
    int bid = blockIdx.x;
    if (bid < 4096) {
        int i = (bid * 256 + threadIdx.x) * 4;
        float4 v = *(const float4*)(x + i);
        ushort4 o;
        o.x = f2bf(v.x); o.y = f2bf(v.y); o.z = f2bf(v.z); o.w = f2bf(v.w);
        *(ushort4*)(x_b + i) = o;
    } else if (bid < 4096 + 768) {
        int t = bid - 4096;
        transpose_tile(w_qkv, wqkv_t, 1024, 3072, (t / 48) * 64, (t % 48) * 64, tile);
    } else {
        int t = bid - 4864;
        transpose_tile(w_out, wout_t, 1024, 1024, (t >> 4) * 64, (t & 15) * 64, tile);
    }
}

// ---------------------------------------------------------------- GEMM: C = A * Bt^T + bias
// m97 structure. QKV mode: cols [0,2048) -> qkv (stride 2048); cols [2048,3072) -> vT

template<bool OUT_BF16, bool QKV>
__global__ __launch_bounds__(256, 3) void gemm_bt(
    const unsigned short* __restrict__ A,
    const unsigned short* __restrict__ Bt,
    const float* __restrict__ bias,
    void* __restrict__ C,
    unsigned short* __restrict__ vTp,
    int M, int N, int K)
{
    __shared__ __align__(16) unsigned short As[128 * 32];
    __shared__ __align__(16) unsigned short Bs[128 * 32];
    const int tid = threadIdx.x;
    const int lane = tid & 63;
    const int wave = tid >> 6;
    const int wr = wave >> 1, wc = wave & 1;
    const int m0 = blockIdx.x * 128, n0 = blockIdx.y * 128;
    const int fr = lane & 15, fq = lane >> 4;

    f32x4 acc[4][4] = {};

    const int grow = lane >> 2;
    const int gcol = (lane & 3) * 8;
    const unsigned short* Ag = A  + (size_t)(m0 + wave * 32 + grow) * K + gcol;
    const unsigned short* Bg = Bt + (size_t)(n0 + wave * 32 + grow) * K + gcol;
    unsigned short* AsW0 = As + (wave * 32) * 32;
    unsigned short* AsW1 = As + (wave * 32 + 16) * 32;
    unsigned short* BsW0 = Bs + (wave * 32) * 32;
    unsigned short* BsW1 = Bs + (wave * 32 + 16) * 32;

    for (int k0 = 0; k0 < K; k0 += 32) {
        __syncthreads();
        ASYNC16(Ag + k0,          AsW0);
        ASYNC16(Ag + 16 * K + k0, AsW1);
        ASYNC16(Bg + k0,          BsW0);
        ASYNC16(Bg + 16 * K + k0, BsW1);
        __syncthreads();

        short8 af[4], bfr[4];
#pragma unroll
        for (int i = 0; i < 4; i++)
            af[i] = *(const short8*)(As + (wr * 64 + i * 16 + fr) * 32 + fq * 8);
#pragma unroll
        for (int j = 0; j < 4; j++)
            bfr[j] = *(const short8*)(Bs + (wc * 64 + j * 16 + fr) * 32 + fq * 8);
#pragma unroll
        for (int i = 0; i < 4; i++)
#pragma unroll
            for (int j = 0; j < 4; j++)
                acc[i][j] = __builtin_amdgcn_mfma_f32_16x16x32_bf16(af[i], bfr[j], acc[i][j], 0, 0, 0);
    }

#pragma unroll
    for (int i = 0; i < 4; i++)
#pragma unroll
        for (int j = 0; j < 4; j++) {
            int col = n0 + wc * 64 + j * 16 + fr;
            float bv = bias[col];
            if (QKV && col >= 2048) {
                int hh = (col - 2048) >> 6, d = col & 63;
#pragma unroll
                for (int r = 0; r < 4; r++) {
                    int row = m0 + wr * 64 + i * 16 + fq * 4 + r;
                    int bb = row >> 11, s = row & 2047;
                    vTp[((size_t)(bb * 16 + hh) * 64 + d) * 2048 + s] = f2bf(acc[i][j][r] + bv);
                }
            } else {
                const int cstride = QKV ? 2048 : N;
#pragma unroll
                for (int r = 0; r < 4; r++) {
                    int row = m0 + wr * 64 + i * 16 + fq * 4 + r;
                    float v = acc[i][j][r] + bv;
                    if (OUT_BF16)
                        ((unsigned short*)C)[(size_t)row * cstride + col] = f2bf(v);
                    else
                        ((float*)C)[(size_t)row * cstride + col] = v;
                }
            }
        }
}

// ---------------------------------------------------------------- flash attention (causal, 2-way key-split)
// TRANSPOSED-SCORE, in-register P (no LDS round-trip). 256-thr blocks (4 waves),
// each wave owns 2 rg x 16 q-rows (rg0 = tile p, rg1 = tile 31-p), rows [w*16,+16).
// ~140 VGPR live -> launch_bounds(256,3) cap 170: NO spill (R7/R8: tighter caps
// spill o_acc to scratch at 10x cost). Grid 1024 = 4 blocks/CU fully resident.
// V LDS uses rotation swizzle: key k of dim d at elem (k - (d&3)*8) & 31 ->
// vf b64 bank starts all-distinct (4-way, was 8-way). Staging still ASYNC16
// (rotation folded into per-lane GLOBAL address; LDS dest stays lane-contiguous).
// Fixed-shift softmax p=exp(s/8-8) => key-split partials exactly additive.

template<int RG0>   // 0: both rg active; 1: only rg1 (jt > p)
__device__ __forceinline__ void attn_step(
    const unsigned short* __restrict__ Ks0, const unsigned short* __restrict__ Ks1,
    const unsigned short* __restrict__ Vs0, const unsigned short* __restrict__ Vs1,
    const short8 (&qf)[2][2], const short8 ones,
    f32x4 (&o_acc)[2][4], f32x4 (&l_acc)[2],
    int j0, int fr, int fq,
    const int (&qrow0)[2], bool diagA, bool diagB)
{
    short8 kf[4][2];
#pragma unroll
    for (int t = 0; t < 4; t++) {
        kf[t][0] = *(const short8*)(Ks0 + (t * 16 + fr) * 32 + fq * 8);
        kf[t][1] = *(const short8*)(Ks1 + (t * 16 + fr) * 32 + fq * 8);
    }

    short8 pf[2][2];   // per-rg PV B-fragments, assembled in registers
#pragma unroll
    for (int rg = RG0; rg < 2; rg++) {
        f32x4 s[4];
#pragma unroll
        for (int t = 0; t < 4; t++) {
            s[t] = (f32x4){0.f, 0.f, 0.f, 0.f};
            // SWAPPED operands: D = S^T tile, [key=fq*4+r][q=fr]
            s[t] = __builtin_amdgcn_mfma_f32_16x16x32_bf16(kf[t][0], qf[rg][0], s[t], 0, 0, 0);
            s[t] = __builtin_amdgcn_mfma_f32_16x16x32_bf16(kf[t][1], qf[rg][1], s[t], 0, 0, 0);
        }
        const bool diag = rg ? diagB : diagA;
        unsigned int pk[4][2];
        if (diag) {   // wave-uniform branch: mask cost only on diagonal tiles
            const int qq = qrow0[rg] + fr;
#pragma unroll
            for (int t = 0; t < 4; t++) {
                const int keyb = j0 + t * 16 + fq * 4;
                float p[4];
#pragma unroll
                for (int r = 0; r < 4; r++) {
                    float v = __expf(s[t][r] * 0.125f - 8.0f);
                    if (keyb + r > qq) v = 0.f;
                    p[r] = v;
                }
                pk[t][0] = pkbf_trunc(p[0], p[1]);
                pk[t][1] = pkbf_trunc(p[2], p[3]);
            }
        } else {
#pragma unroll
            for (int t = 0; t < 4; t++) {
                float p[4];
#pragma unroll
                for (int r = 0; r < 4; r++)
                    p[r] = __expf(s[t][r] * 0.125f - 8.0f);
                pk[t][0] = pkbf_trunc(p[0], p[1]);
                pk[t][1] = pkbf_trunc(p[2], p[3]);
            }
        }
        pf[rg][0] = __builtin_bit_cast(short8, (uint4v){pk[0][0], pk[0][1], pk[1][0], pk[1][1]});
        pf[rg][1] = __builtin_bit_cast(short8, (uint4v){pk[2][0], pk[2][1], pk[3][0], pk[3][1]});
    }

    // O^T += V^T P ; l += 1 P    (A = V fragment in sigma key-order, B = pf)
    const int rot = (fr & 3) * 8;                    // matches staging rotation
    const int eo_lo = (fq * 4 - rot) & 31;
    const int eo_hi = (fq * 4 + 16 - rot) & 31;
#pragma unroll
    for (int ks = 0; ks < 2; ks++) {
        const unsigned short* Vsb = ks ? Vs1 : Vs0;
#pragma unroll
        for (int t = 0; t < 4; t++) {
            short4v vlo = *(const short4v*)(Vsb + (t * 16 + fr) * 32 + eo_lo);
            short4v vhi = *(const short4v*)(Vsb + (t * 16 + fr) * 32 + eo_hi);
            short8 vf = (short8){vlo[0], vlo[1], vlo[2], vlo[3], vhi[0], vhi[1], vhi[2], vhi[3]};
#pragma unroll
            for (int rg = RG0; rg < 2; rg++)
                o_acc[rg][t] = __builtin_amdgcn_mfma_f32_16x16x32_bf16(vf, pf[rg][ks], o_acc[rg][t], 0, 0, 0);
        }
#pragma unroll
        for (int rg = RG0; rg < 2; rg++)
            l_acc[rg] = __builtin_amdgcn_mfma_f32_16x16x32_bf16(ones, pf[rg][ks], l_acc[rg], 0, 0, 0);
    }
}

__global__ __launch_bounds__(256, 3) void flash_attn(
    const unsigned short* __restrict__ qkv,   // (B*S, 2048): Q | K
    const unsigned short* __restrict__ vT,    // (B*16 heads, 64 dims, 2048 keys)
    unsigned short* __restrict__ Opart,       // [2][B*S][1024] bf16 partial O
    float* __restrict__ lpart)                // [2][B*S][16] f32 partial l
{
    const int gid = blockIdx.x;               // 1024
    const int bh = gid & 31;                  // fastest -> same-bh blocks on same XCD
    const int sl = gid >> 5;                  // 0..31
    const int p  = sl & 15;                   // q-tile pair {p, 31-p}
    const int g  = sl >> 4;                   // key half
    const int h = bh & 15, b = bh >> 4;
    const int tid = threadIdx.x, wave = tid >> 6, lane = tid & 63;
    const int fr = lane & 15, fq = lane >> 4;
    const size_t RS = 2048;

    const unsigned short* Qb = qkv + (size_t)b * 2048 * RS + h * 64;
    const unsigned short* Kb = Qb + 1024;
    const unsigned short* Vt = vT + (size_t)(b * 16 + h) * 64 * 2048;

    __shared__ __align__(16) unsigned short Ks[2][64 * 32];   // [dim-half][key][32 dims]
    __shared__ __align__(16) unsigned short Vs[2][64 * 32];   // [key-half][dim][32 keys, rot-swizzled]

    short8 qf[2][2];
    int qrow0[2];
#pragma unroll
    for (int rg = 0; rg < 2; rg++) {
        int qt = rg ? (31 - p) : p;
        qrow0[rg] = qt * 64 + wave * 16;
        const unsigned short* qrow = Qb + (size_t)(qrow0[rg] + fr) * RS;
        qf[rg][0] = *(const short8*)(qrow + fq * 8);
        qf[rg][1] = *(const short8*)(qrow + 32 + fq * 8);
    }
    short8 ones;
#pragma unroll
    for (int e = 0; e < 8; e++) ones[e] = (short)0x3F80;

    f32x4 o_acc[2][4] = {};
    f32x4 l_acc[2] = {};

    // staging: wave w covers 16 rows; lane l -> row w*16 + l/4, 8 elems at (l&3)*8
    const int grow = lane >> 2;
    const int gcol = (lane & 3) * 8;
    const int vrot = (grow & 3) * 8;                       // V rotation (dim = w*16+grow; w*16%4==0)
    const int vcol = (gcol + vrot) & 31;
    const unsigned short* Kg = Kb + (size_t)(wave * 16 + grow) * RS + gcol;
    const unsigned short* Vg = Vt + (size_t)(wave * 16 + grow) * 2048 + vcol;
    unsigned short* KsW0 = Ks[0] + (wave * 16) * 32;
    unsigned short* KsW1 = Ks[1] + (wave * 16) * 32;
    unsigned short* VsW0 = Vs[0] + (wave * 16) * 32;
    unsigned short* VsW1 = Vs[1] + (wave * 16) * 32;

    // balanced 2-way split over weighted units (2 while jt<=p, else 1; total 33): 17/16
    const int mid = (p >= 8) ? 8 : (16 - p);
    const int lo = g ? mid : 0;
    const int hi = g ? (32 - p) : mid;

    for (int jt = lo; jt < hi; jt++) {
        const int j0 = jt * 64;
        __syncthreads();
        ASYNC16(Kg + (size_t)j0 * RS,      KsW0);
        ASYNC16(Kg + (size_t)j0 * RS + 32, KsW1);
        ASYNC16(Vg + j0,      VsW0);
        ASYNC16(Vg + j0 + 32, VsW1);
        __syncthreads();

        bool diagA = (jt == p), diagB = (jt == 31 - p);
        if (jt <= p)
            attn_step<0>(Ks[0], Ks[1], Vs[0], Vs[1], qf, ones,
                         o_acc, l_acc, j0, fr, fq, qrow0, diagA, diagB);
        else
            attn_step<1>(Ks[0], Ks[1], Vs[0], Vs[1], qf, ones,
                         o_acc, l_acc, j0, fr, fq, qrow0, diagA, diagB);
    }

    // write partials: O^T layout -> lane (fr,fq) holds O[q=qrow0+fr][d=t*16+fq*4+r]
    unsigned short* Og = Opart + (size_t)g * 4096 * 1024;
    float* lg = lpart + (size_t)g * 4096 * 16;
#pragma unroll
    for (int rg = 0; rg < 2; rg++) {
        const size_t rowbase = (size_t)(b * 2048 + qrow0[rg] + fr) * 1024 + h * 64;
#pragma unroll
        for (int t = 0; t < 4; t++) {
            ushort4 o;
            o.x = f2bf(o_acc[rg][t][0]); o.y = f2bf(o_acc[rg][t][1]);
            o.z = f2bf(o_acc[rg][t][2]); o.w = f2bf(o_acc[rg][t][3]);
            *(ushort4*)(Og + rowbase + t * 16 + fq * 4) = o;
        }
        if (fq == 0)
            lg[(size_t)(b * 2048 + qrow0[rg] + fr) * 16 + h] = l_acc[rg][0];
    }
}

// ---------------------------------------------------------------- combine key-split partials (2-way)
__global__ __launch_bounds__(256) void reduce_attn(
    const unsigned short* __restrict__ Opart, const float* __restrict__ lpart,
    unsigned short* __restrict__ out)
{
    const size_t OP = (size_t)4096 * 1024, LP = (size_t)4096 * 16;
    int i = (blockIdx.x * 256 + threadIdx.x) * 8;     // over 4096*1024
    int row = i >> 10, h = (i & 1023) >> 6;
    float lsum = lpart[row * 16 + h] + lpart[LP + row * 16 + h];
    float inv = 1.0f / lsum;
    ushort4 a0 = *(const ushort4*)(Opart + i);
    ushort4 a1 = *(const ushort4*)(Opart + i + 4);
    ushort4 b0 = *(const ushort4*)(Opart + OP + i);
    ushort4 b1 = *(const ushort4*)(Opart + OP + i + 4);
    ushort4 o0, o1;
    o0.x = f2bf((bf2f(a0.x) + bf2f(b0.x)) * inv);
    o0.y = f2bf((bf2f(a0.y) + bf2f(b0.y)) * inv);
    o0.z = f2bf((bf2f(a0.z) + bf2f(b0.z)) * inv);
    o0.w = f2bf((bf2f(a0.w) + bf2f(b0.w)) * inv);
    o1.x = f2bf((bf2f(a1.x) + bf2f(b1.x)) * inv);
    o1.y = f2bf((bf2f(a1.y) + bf2f(b1.y)) * inv);
    o1.z = f2bf((bf2f(a1.z) + bf2f(b1.z)) * inv);
    o1.w = f2bf((bf2f(a1.w) + bf2f(b1.w)) * inv);
    *(ushort4*)(out + i) = o0;
    *(ushort4*)(out + i + 4) = o1;
}

// ----------------------------------------------------------------
extern "C" void kernel_launch(void* const* d_in, const int* in_sizes, int n_in,
                              void* d_out, int out_size, void* d_ws, size_t ws_size,
                              hipStream_t stream) {
    const float* x      = (const float*)d_in[0];
    const float* w_qkv  = (const float*)d_in[1];
    const float* b_qkv  = (const float*)d_in[2];
    const float* w_out  = (const float*)d_in[3];
    const float* b_out  = (const float*)d_in[4];
    float* out = (float*)d_out;

    // Workspace layout (60 MB, dead-region reuse: Opart overlays x_b+wqkv_t which
    // die after the QKV GEMM):
    char* ws = (char*)d_ws;
    const size_t MB = 1024 * 1024;
    unsigned short* qkv    = (unsigned short*)(ws);              //  0..16  (gemm1 -> flash)
    unsigned short* vT     = (unsigned short*)(ws + 16 * MB);    // 16..24  (gemm1 -> flash)
    unsigned short* wout_t = (unsigned short*)(ws + 24 * MB);    // 24..26  (prep -> gemm2)
    unsigned short* attn   = (unsigned short*)(ws + 26 * MB);    // 26..34  (reduce -> gemm2)
    float*          lpart  = (float*)         (ws + 34 * MB);    // 34..35  (flash -> reduce)
    unsigned short* x_b    = (unsigned short*)(ws + 36 * MB);    // 36..44  (prep -> gemm1, dead after)
    unsigned short* wqkv_t = (unsigned short*)(ws + 44 * MB);    // 44..50  (prep -> gemm1, dead after)
    unsigned short* Opart  = (unsigned short*)(ws + 36 * MB);    // 36..52  (flash -> reduce; reuses dead region)

    prep<<<5120, 256, 0, stream>>>(x, w_qkv, w_out, x_b, wqkv_t, wout_t);
    gemm_bt<true, true ><<<dim3(32, 24), 256, 0, stream>>>(x_b,  wqkv_t, b_qkv, qkv, vT, 4096, 3072, 1024);
    flash_attn<<<1024, 256, 0, stream>>>(qkv, vT, Opart, lpart);
    reduce_attn<<<2048, 256, 0, stream>>>(Opart, lpart, attn);
    gemm_bt<false, false><<<dim3(32, 8),  256, 0, stream>>>(attn, wout_t, b_out, out, nullptr, 4096, 1024, 1024);
}